// Round 3
// baseline (412.859 us; speedup 1.0000x reference)
//
#include <hip/hip_runtime.h>
#include <math.h>

#define E_DIM 64
#define N_E   1024
#define BETA  0.25

// ---------------------------------------------------------------------------
// Replicates the numpy float32 reference:
//   nz_i = np.sum(zf*zf, axis=1)        (products rounded, pairwise-8 sum)
//   h_j  = np.sum(cb*cb, axis=1)        (same)
//   m_ij = (2*zf) @ cb.T                (fp32 FMA chain, k ascending, init 0)
//   d_ij = fp32( fp32(nz_i + h_j) - m_ij )
//   idx  = argmin_j d_ij, strict <, first index on ties
// The ulp(64) quantization of d is the dominant rounding; tree-order noise in
// nz (uniform row shift) and m (~1e-9) is argmin-invariant to ~1e-4/element.
//
// ws layout: [0,4096) uint hist[1024]; [4096,4104) double sse; [4112,8208) h
// ---------------------------------------------------------------------------

// numpy scalar pairwise pattern for n=64: 8 accumulators over rounded products,
// combine ((r0+r1)+(r2+r3))+((r4+r5)+(r6+r7)).
__device__ __forceinline__ float pw64_sq(const float* v) {
    float r[8];
#pragma unroll
    for (int l = 0; l < 8; ++l) r[l] = v[l] * v[l];
#pragma unroll
    for (int t = 1; t < 8; ++t)
#pragma unroll
        for (int l = 0; l < 8; ++l) r[l] += v[8 * t + l] * v[8 * t + l];
    return ((r[0] + r[1]) + (r[2] + r[3])) + ((r[4] + r[5]) + (r[6] + r[7]));
}

__global__ __launch_bounds__(256) void k_h(const float* __restrict__ cb,
                                           float* __restrict__ h) {
    int j = blockIdx.x * 256 + threadIdx.x;
    if (j < N_E) {
        float e[E_DIM];
        const float4* ep = reinterpret_cast<const float4*>(cb + (size_t)j * E_DIM);
#pragma unroll
        for (int k4 = 0; k4 < E_DIM / 4; ++k4) {
            float4 v = ep[k4];
            e[4 * k4 + 0] = v.x; e[4 * k4 + 1] = v.y;
            e[4 * k4 + 2] = v.z; e[4 * k4 + 3] = v.w;
        }
        h[j] = pw64_sq(e);
    }
}

__global__ __launch_bounds__(256) void k_scan(
    const float* __restrict__ z, const float* __restrict__ cb,
    const float* __restrict__ h,
    float* __restrict__ out_zq, float* __restrict__ out_idx,
    unsigned* __restrict__ hist, double* __restrict__ sse) {
    const int row = blockIdx.x * 256 + threadIdx.x;

    // load z row (16B-aligned), compute nz from UNSCALED z, then scale by 2
    float tz[E_DIM];
    const float4* zp = reinterpret_cast<const float4*>(z + (size_t)row * E_DIM);
#pragma unroll
    for (int k4 = 0; k4 < E_DIM / 4; ++k4) {
        float4 v = zp[k4];
        tz[4 * k4 + 0] = v.x; tz[4 * k4 + 1] = v.y;
        tz[4 * k4 + 2] = v.z; tz[4 * k4 + 3] = v.w;
    }
    const float nz = pw64_sq(tz);
#pragma unroll
    for (int k = 0; k < E_DIM; ++k) tz[k] = 2.0f * tz[k];   // exact

    float b0 = INFINITY;
    int bi = 0;
#pragma unroll 1
    for (int j = 0; j < N_E; j += 4) {
        const float* c0 = cb + (size_t)j * E_DIM;   // wave-uniform -> s_load
        float m0 = 0.f, m1 = 0.f, m2 = 0.f, m3 = 0.f;
#pragma unroll
        for (int k = 0; k < E_DIM; ++k) {
            float wk = tz[k];
            m0 = fmaf(wk, c0[0 * E_DIM + k], m0);
            m1 = fmaf(wk, c0[1 * E_DIM + k], m1);
            m2 = fmaf(wk, c0[2 * E_DIM + k], m2);
            m3 = fmaf(wk, c0[3 * E_DIM + k], m3);
        }
        // d = round(round(nz + h_j) - m_j)  -- plain fp32 ops, no fma here
        float s0 = (nz + h[j + 0]) - m0;
        float s1 = (nz + h[j + 1]) - m1;
        float s2 = (nz + h[j + 2]) - m2;
        float s3 = (nz + h[j + 3]) - m3;
        // ascending j, strict < == np.argmin first-occurrence
        if (s0 < b0) { b0 = s0; bi = j + 0; }
        if (s1 < b0) { b0 = s1; bi = j + 1; }
        if (s2 < b0) { b0 = s2; bi = j + 2; }
        if (s3 < b0) { b0 = s3; bi = j + 3; }
    }

    out_idx[row] = (float)bi;

    // z_q row: scalar stores (out+1 base is only 4B-aligned)
    float local = 0.f;
    const float4* cv = reinterpret_cast<const float4*>(cb + (size_t)bi * E_DIM);
    float* orow = out_zq + (size_t)row * E_DIM;
#pragma unroll
    for (int k4 = 0; k4 < E_DIM / 4; ++k4) {
        float4 c = cv[k4];
        float zx = 0.5f * tz[4 * k4 + 0], zy = 0.5f * tz[4 * k4 + 1];
        float zz = 0.5f * tz[4 * k4 + 2], zw = 0.5f * tz[4 * k4 + 3];
        orow[4 * k4 + 0] = c.x; orow[4 * k4 + 1] = c.y;
        orow[4 * k4 + 2] = c.z; orow[4 * k4 + 3] = c.w;
        float dx = c.x - zx, dy = c.y - zy, dz = c.z - zz, dw = c.w - zw;
        local = fmaf(dx, dx, local);
        local = fmaf(dy, dy, local);
        local = fmaf(dz, dz, local);
        local = fmaf(dw, dw, local);
    }
    atomicAdd(&hist[bi], 1u);

    // block-reduce SSE -> one double atomic per block
#pragma unroll
    for (int off = 32; off; off >>= 1) local += __shfl_down(local, off);
    __shared__ float wpart[4];
    if ((threadIdx.x & 63) == 0) wpart[threadIdx.x >> 6] = local;
    __syncthreads();
    if (threadIdx.x == 0) {
        float t = wpart[0] + wpart[1] + wpart[2] + wpart[3];
        atomicAdd(sse, (double)t);
    }
}

__global__ __launch_bounds__(256) void k_final(
    const unsigned* __restrict__ hist, const double* __restrict__ sse,
    float* __restrict__ out, int nrows) {
    __shared__ double sh[256];
    double acc = 0.0;
    for (int j = threadIdx.x; j < N_E; j += 256) {
        double p = (double)hist[j] / (double)nrows;
        acc += p * log(p + 1e-10);
    }
    sh[threadIdx.x] = acc;
    __syncthreads();
    for (int s = 128; s; s >>= 1) {
        if (threadIdx.x < s) sh[threadIdx.x] += sh[threadIdx.x + s];
        __syncthreads();
    }
    if (threadIdx.x == 0) {
        double ntot = (double)nrows * (double)E_DIM;
        out[0] = (float)((1.0 + BETA) * (*sse) / ntot);               // loss
        out[1 + (size_t)nrows * E_DIM] = (float)exp(-sh[0]);          // perplexity
    }
}

extern "C" void kernel_launch(void* const* d_in, const int* in_sizes, int n_in,
                              void* d_out, int out_size, void* d_ws, size_t ws_size,
                              hipStream_t stream) {
    const float* z  = (const float*)d_in[0];
    const float* cb = (const float*)d_in[1];
    const int nrows = in_sizes[0] / E_DIM;   // 65536
    float* out = (float*)d_out;

    char* ws = (char*)d_ws;
    unsigned* hist = (unsigned*)(ws + 0);
    double*   sse  = (double*)  (ws + 4096);
    float*    h    = (float*)   (ws + 4112);

    float* out_zq  = out + 1;
    float* out_idx = out + 1 + (size_t)nrows * E_DIM + 1;

    hipMemsetAsync(d_ws, 0, 4112, stream);  // hist + sse
    k_h<<<(N_E + 255) / 256, 256, 0, stream>>>(cb, h);
    k_scan<<<nrows / 256, 256, 0, stream>>>(z, cb, h, out_zq, out_idx, hist, sse);
    k_final<<<1, 256, 0, stream>>>(hist, sse, out, nrows);
}

// Round 4
// 171.655 us; speedup vs baseline: 2.4052x; 2.4052x over previous
//
#include <hip/hip_runtime.h>
#include <math.h>

#define E_DIM 64
#define N_E   1024
#define BETA  0.25

// ---------------------------------------------------------------------------
// Numerics (MUST stay bit-identical to the passing round-3 kernel):
//   nz_i = pairwise-8 sum of rounded z*z        (pw64_sq)
//   h_j  = pairwise-8 sum of rounded e*e        (pw64_sq)
//   m_ij = sequential fp32 FMA chain, k=0..63 ascending, init 0, weights 2*z
//   d_ij = fp32( fp32(nz_i + h_j) - m_ij )      (plain ops, no fma)
//   idx  = argmin_j d, strict <, first index on ties
// Codebook-split across waves is argmin-exact: per-element d unchanged;
// merge over ascending disjoint chunks with strict < == first-index argmin.
//
// ws layout: [0,4096) uint hist[1024]; [4096,4104) double sse; [4112,8208) h
// ---------------------------------------------------------------------------

__device__ __forceinline__ float pw64_sq(const float* v) {
    float r[8];
#pragma unroll
    for (int l = 0; l < 8; ++l) r[l] = v[l] * v[l];
#pragma unroll
    for (int t = 1; t < 8; ++t)
#pragma unroll
        for (int l = 0; l < 8; ++l) r[l] += v[8 * t + l] * v[8 * t + l];
    return ((r[0] + r[1]) + (r[2] + r[3])) + ((r[4] + r[5]) + (r[6] + r[7]));
}

__global__ __launch_bounds__(256) void k_h(const float* __restrict__ cb,
                                           float* __restrict__ h) {
    int j = blockIdx.x * 256 + threadIdx.x;
    if (j < N_E) {
        float e[E_DIM];
        const float4* ep = reinterpret_cast<const float4*>(cb + (size_t)j * E_DIM);
#pragma unroll
        for (int k4 = 0; k4 < E_DIM / 4; ++k4) {
            float4 v = ep[k4];
            e[4 * k4 + 0] = v.x; e[4 * k4 + 1] = v.y;
            e[4 * k4 + 2] = v.z; e[4 * k4 + 3] = v.w;
        }
        h[j] = pw64_sq(e);
    }
}

// Block = 4 waves x 64 lanes. Lane owns a row; wave w owns codebook chunk w.
// __launch_bounds__(256, 4): 4 waves/EU floor -> VGPR cap 128 (tz stays in regs).
__global__ __launch_bounds__(256, 4) void k_scan(
    const float* __restrict__ z, const float* __restrict__ cb,
    const float* __restrict__ h,
    float* __restrict__ out_zq, float* __restrict__ out_idx,
    unsigned* __restrict__ hist, double* __restrict__ sse) {
    const int lane = threadIdx.x & 63;
    // readfirstlane: make the chunk id provably wave-uniform -> cb via s_load
    const int w = __builtin_amdgcn_readfirstlane(threadIdx.x >> 6);
    const int row = blockIdx.x * 64 + lane;

    // load z row (16B-aligned), nz from UNSCALED z, then scale by 2 (exact)
    float tz[E_DIM];
    const float4* zp = reinterpret_cast<const float4*>(z + (size_t)row * E_DIM);
#pragma unroll
    for (int k4 = 0; k4 < E_DIM / 4; ++k4) {
        float4 v = zp[k4];
        tz[4 * k4 + 0] = v.x; tz[4 * k4 + 1] = v.y;
        tz[4 * k4 + 2] = v.z; tz[4 * k4 + 3] = v.w;
    }
    const float nz = pw64_sq(tz);
#pragma unroll
    for (int k = 0; k < E_DIM; ++k) tz[k] = 2.0f * tz[k];

    float b0 = INFINITY;
    int bi = 0;
    const int j0 = w * (N_E / 4);
#pragma unroll 1
    for (int j = j0; j < j0 + N_E / 4; j += 4) {
        const float* c0 = cb + (size_t)j * E_DIM;   // wave-uniform -> s_load
        float m0 = 0.f, m1 = 0.f, m2 = 0.f, m3 = 0.f;
#pragma unroll
        for (int k = 0; k < E_DIM; ++k) {
            float wk = tz[k];
            m0 = fmaf(wk, c0[0 * E_DIM + k], m0);
            m1 = fmaf(wk, c0[1 * E_DIM + k], m1);
            m2 = fmaf(wk, c0[2 * E_DIM + k], m2);
            m3 = fmaf(wk, c0[3 * E_DIM + k], m3);
        }
        float s0 = (nz + h[j + 0]) - m0;
        float s1 = (nz + h[j + 1]) - m1;
        float s2 = (nz + h[j + 2]) - m2;
        float s3 = (nz + h[j + 3]) - m3;
        if (s0 < b0) { b0 = s0; bi = j + 0; }
        if (s1 < b0) { b0 = s1; bi = j + 1; }
        if (s2 < b0) { b0 = s2; bi = j + 2; }
        if (s3 < b0) { b0 = s3; bi = j + 3; }
    }

    // merge the 4 chunk-partials per row via LDS (ascending chunk order)
    __shared__ float lb[4][64];
    __shared__ int   li[4][64];
    lb[w][lane] = b0;
    li[w][lane] = bi;
    __syncthreads();

    if (threadIdx.x < 64) {
        float b = lb[0][lane];
        int   i = li[0][lane];
#pragma unroll
        for (int c = 1; c < 4; ++c) {
            float bc = lb[c][lane];
            int   ic = li[c][lane];
            if (bc < b) { b = bc; i = ic; }   // strict < keeps lowest chunk/index
        }
        out_idx[row] = (float)i;

        // z_q row: scalar stores (out+1 base is only 4B-aligned)
        float local = 0.f;
        const float4* cv = reinterpret_cast<const float4*>(cb + (size_t)i * E_DIM);
        float* orow = out_zq + (size_t)row * E_DIM;
#pragma unroll
        for (int k4 = 0; k4 < E_DIM / 4; ++k4) {
            float4 c = cv[k4];
            float zx = 0.5f * tz[4 * k4 + 0], zy = 0.5f * tz[4 * k4 + 1];
            float zz = 0.5f * tz[4 * k4 + 2], zw = 0.5f * tz[4 * k4 + 3];
            orow[4 * k4 + 0] = c.x; orow[4 * k4 + 1] = c.y;
            orow[4 * k4 + 2] = c.z; orow[4 * k4 + 3] = c.w;
            float dx = c.x - zx, dy = c.y - zy, dz = c.z - zz, dw = c.w - zw;
            local = fmaf(dx, dx, local);
            local = fmaf(dy, dy, local);
            local = fmaf(dz, dz, local);
            local = fmaf(dw, dw, local);
        }
        atomicAdd(&hist[i], 1u);

        // wave-0 reduce SSE -> one double atomic per block
#pragma unroll
        for (int off = 32; off; off >>= 1) local += __shfl_down(local, off);
        if (lane == 0) atomicAdd(sse, (double)local);
    }
}

__global__ __launch_bounds__(256) void k_final(
    const unsigned* __restrict__ hist, const double* __restrict__ sse,
    float* __restrict__ out, int nrows) {
    __shared__ double sh[256];
    double acc = 0.0;
    for (int j = threadIdx.x; j < N_E; j += 256) {
        double p = (double)hist[j] / (double)nrows;
        acc += p * log(p + 1e-10);
    }
    sh[threadIdx.x] = acc;
    __syncthreads();
    for (int s = 128; s; s >>= 1) {
        if (threadIdx.x < s) sh[threadIdx.x] += sh[threadIdx.x + s];
        __syncthreads();
    }
    if (threadIdx.x == 0) {
        double ntot = (double)nrows * (double)E_DIM;
        out[0] = (float)((1.0 + BETA) * (*sse) / ntot);               // loss
        out[1 + (size_t)nrows * E_DIM] = (float)exp(-sh[0]);          // perplexity
    }
}

extern "C" void kernel_launch(void* const* d_in, const int* in_sizes, int n_in,
                              void* d_out, int out_size, void* d_ws, size_t ws_size,
                              hipStream_t stream) {
    const float* z  = (const float*)d_in[0];
    const float* cb = (const float*)d_in[1];
    const int nrows = in_sizes[0] / E_DIM;   // 65536
    float* out = (float*)d_out;

    char* ws = (char*)d_ws;
    unsigned* hist = (unsigned*)(ws + 0);
    double*   sse  = (double*)  (ws + 4096);
    float*    h    = (float*)   (ws + 4112);

    float* out_zq  = out + 1;
    float* out_idx = out + 1 + (size_t)nrows * E_DIM + 1;

    hipMemsetAsync(d_ws, 0, 4112, stream);  // hist + sse
    k_h<<<(N_E + 255) / 256, 256, 0, stream>>>(cb, h);
    k_scan<<<nrows / 64, 256, 0, stream>>>(z, cb, h, out_zq, out_idx, hist, sse);
    k_final<<<1, 256, 0, stream>>>(hist, sse, out, nrows);
}

// Round 5
// 165.298 us; speedup vs baseline: 2.4977x; 1.0385x over previous
//
#include <hip/hip_runtime.h>
#include <math.h>

#define E_DIM 64
#define N_E   1024
#define NWAVE 8                 // codebook split: wave w scans codes [128w,128w+128)
#define CHUNK (N_E / NWAVE)     // 128
#define BETA  0.25

// ---------------------------------------------------------------------------
// Numerics (MUST stay bit-identical to the passing round-3/4 kernels):
//   nz_i = pairwise-8 sum of rounded z*z        (pw64_sq)
//   h_j  = pairwise-8 sum of rounded e*e        (pw64_sq)
//   m_ij = sequential fp32 FMA chain, k=0..63 ascending, init 0, weights 2*z
//   d_ij = fp32( fp32(nz_i + h_j) - m_ij )      (plain ops, no fma)
//   idx  = argmin_j d, strict <, first index on ties
// Codebook-split across 8 waves is argmin-exact: per-element d unchanged;
// merge over ascending disjoint chunks with strict < == first-index argmin.
//
// ws layout: [0,4096) uint hist[1024]; [4096,4104) double sse; [4112,8208) h
// ---------------------------------------------------------------------------

__device__ __forceinline__ float pw64_sq(const float* v) {
    float r[8];
#pragma unroll
    for (int l = 0; l < 8; ++l) r[l] = v[l] * v[l];
#pragma unroll
    for (int t = 1; t < 8; ++t)
#pragma unroll
        for (int l = 0; l < 8; ++l) r[l] += v[8 * t + l] * v[8 * t + l];
    return ((r[0] + r[1]) + (r[2] + r[3])) + ((r[4] + r[5]) + (r[6] + r[7]));
}

__global__ __launch_bounds__(256) void k_h(const float* __restrict__ cb,
                                           float* __restrict__ h) {
    int j = blockIdx.x * 256 + threadIdx.x;
    if (j < N_E) {
        float e[E_DIM];
        const float4* ep = reinterpret_cast<const float4*>(cb + (size_t)j * E_DIM);
#pragma unroll
        for (int k4 = 0; k4 < E_DIM / 4; ++k4) {
            float4 v = ep[k4];
            e[4 * k4 + 0] = v.x; e[4 * k4 + 1] = v.y;
            e[4 * k4 + 2] = v.z; e[4 * k4 + 3] = v.w;
        }
        h[j] = pw64_sq(e);
    }
}

// Block = 8 waves x 64 lanes; lane owns a row, wave w owns codebook chunk w.
// __launch_bounds__(512, 2): VGPR cap 128 (spill-safe); actual ~90 -> 5 waves/SIMD.
__global__ __launch_bounds__(512, 2) void k_scan(
    const float* __restrict__ z, const float* __restrict__ cb,
    const float* __restrict__ h,
    float* __restrict__ out_zq, float* __restrict__ out_idx,
    unsigned* __restrict__ hist, double* __restrict__ sse) {
    const int lane = threadIdx.x & 63;
    // readfirstlane: chunk id provably wave-uniform -> codebook via s_load
    const int w = __builtin_amdgcn_readfirstlane(threadIdx.x >> 6);
    const int row = blockIdx.x * 64 + lane;

    // load z row (16B-aligned), nz from UNSCALED z, then scale by 2 (exact)
    float tz[E_DIM];
    const float4* zp = reinterpret_cast<const float4*>(z + (size_t)row * E_DIM);
#pragma unroll
    for (int k4 = 0; k4 < E_DIM / 4; ++k4) {
        float4 v = zp[k4];
        tz[4 * k4 + 0] = v.x; tz[4 * k4 + 1] = v.y;
        tz[4 * k4 + 2] = v.z; tz[4 * k4 + 3] = v.w;
    }
    const float nz = pw64_sq(tz);
#pragma unroll
    for (int k = 0; k < E_DIM; ++k) tz[k] = 2.0f * tz[k];

    float b0 = INFINITY;
    int bi = 0;
    const int j0 = w * CHUNK;
#pragma unroll 1
    for (int j = j0; j < j0 + CHUNK; j += 4) {
        const float* c0 = cb + (size_t)j * E_DIM;   // wave-uniform -> s_load
        float m0 = 0.f, m1 = 0.f, m2 = 0.f, m3 = 0.f;
#pragma unroll
        for (int k = 0; k < E_DIM; ++k) {
            float wk = tz[k];
            m0 = fmaf(wk, c0[0 * E_DIM + k], m0);
            m1 = fmaf(wk, c0[1 * E_DIM + k], m1);
            m2 = fmaf(wk, c0[2 * E_DIM + k], m2);
            m3 = fmaf(wk, c0[3 * E_DIM + k], m3);
        }
        float s0 = (nz + h[j + 0]) - m0;
        float s1 = (nz + h[j + 1]) - m1;
        float s2 = (nz + h[j + 2]) - m2;
        float s3 = (nz + h[j + 3]) - m3;
        if (s0 < b0) { b0 = s0; bi = j + 0; }
        if (s1 < b0) { b0 = s1; bi = j + 1; }
        if (s2 < b0) { b0 = s2; bi = j + 2; }
        if (s3 < b0) { b0 = s3; bi = j + 3; }
    }

    // merge the 8 chunk-partials per row via LDS (ascending chunk order)
    __shared__ float lb[NWAVE][64];
    __shared__ int   li[NWAVE][64];
    lb[w][lane] = b0;
    li[w][lane] = bi;
    __syncthreads();

    if (threadIdx.x < 64) {
        float b = lb[0][lane];
        int   i = li[0][lane];
#pragma unroll
        for (int c = 1; c < NWAVE; ++c) {
            float bc = lb[c][lane];
            int   ic = li[c][lane];
            if (bc < b) { b = bc; i = ic; }   // strict < keeps lowest chunk/index
        }
        out_idx[row] = (float)i;

        // z_q row: scalar stores (out+1 base is only 4B-aligned)
        float local = 0.f;
        const float4* cv = reinterpret_cast<const float4*>(cb + (size_t)i * E_DIM);
        float* orow = out_zq + (size_t)row * E_DIM;
#pragma unroll
        for (int k4 = 0; k4 < E_DIM / 4; ++k4) {
            float4 c = cv[k4];
            float zx = 0.5f * tz[4 * k4 + 0], zy = 0.5f * tz[4 * k4 + 1];
            float zz = 0.5f * tz[4 * k4 + 2], zw = 0.5f * tz[4 * k4 + 3];
            orow[4 * k4 + 0] = c.x; orow[4 * k4 + 1] = c.y;
            orow[4 * k4 + 2] = c.z; orow[4 * k4 + 3] = c.w;
            float dx = c.x - zx, dy = c.y - zy, dz = c.z - zz, dw = c.w - zw;
            local = fmaf(dx, dx, local);
            local = fmaf(dy, dy, local);
            local = fmaf(dz, dz, local);
            local = fmaf(dw, dw, local);
        }
        atomicAdd(&hist[i], 1u);

        // wave-0 reduce SSE -> one double atomic per block
#pragma unroll
        for (int off = 32; off; off >>= 1) local += __shfl_down(local, off);
        if (lane == 0) atomicAdd(sse, (double)local);
    }
}

__global__ __launch_bounds__(256) void k_final(
    const unsigned* __restrict__ hist, const double* __restrict__ sse,
    float* __restrict__ out, int nrows) {
    __shared__ double sh[256];
    double acc = 0.0;
    for (int j = threadIdx.x; j < N_E; j += 256) {
        double p = (double)hist[j] / (double)nrows;
        acc += p * log(p + 1e-10);
    }
    sh[threadIdx.x] = acc;
    __syncthreads();
    for (int s = 128; s; s >>= 1) {
        if (threadIdx.x < s) sh[threadIdx.x] += sh[threadIdx.x + s];
        __syncthreads();
    }
    if (threadIdx.x == 0) {
        double ntot = (double)nrows * (double)E_DIM;
        out[0] = (float)((1.0 + BETA) * (*sse) / ntot);               // loss
        out[1 + (size_t)nrows * E_DIM] = (float)exp(-sh[0]);          // perplexity
    }
}

extern "C" void kernel_launch(void* const* d_in, const int* in_sizes, int n_in,
                              void* d_out, int out_size, void* d_ws, size_t ws_size,
                              hipStream_t stream) {
    const float* z  = (const float*)d_in[0];
    const float* cb = (const float*)d_in[1];
    const int nrows = in_sizes[0] / E_DIM;   // 65536
    float* out = (float*)d_out;

    char* ws = (char*)d_ws;
    unsigned* hist = (unsigned*)(ws + 0);
    double*   sse  = (double*)  (ws + 4096);
    float*    h    = (float*)   (ws + 4112);

    float* out_zq  = out + 1;
    float* out_idx = out + 1 + (size_t)nrows * E_DIM + 1;

    hipMemsetAsync(d_ws, 0, 4112, stream);  // hist + sse
    k_h<<<(N_E + 255) / 256, 256, 0, stream>>>(cb, h);
    k_scan<<<nrows / 64, 512, 0, stream>>>(z, cb, h, out_zq, out_idx, hist, sse);
    k_final<<<1, 256, 0, stream>>>(hist, sse, out, nrows);
}